// Round 24
// baseline (187.412 us; speedup 1.0000x reference)
//
#include <hip/hip_runtime.h>

#define N_NODES 50000
#define N_EDGES 800000
#define BN_EPS 1e-5f
#define NB 196          // dst buckets: bucket = dst >> 8
#define BCAP 5120       // bucket capacity (avg 4082, sigma ~64)
#define SCAT_BLOCKS 400 // 2000 edges per block
#define EPB 2000
#define GGRID 391       // gemm blocks
#define NSLAB 3125      // 50000 / 16 exact

typedef __bf16 bf16x8 __attribute__((ext_vector_type(8)));
typedef float f32x4 __attribute__((ext_vector_type(4)));

static __device__ __forceinline__ unsigned short f2b(float f) {
    unsigned int u = __float_as_uint(f);
    return (unsigned short)((u + 0x7FFFu + ((u >> 16) & 1u)) >> 16);   // RNE
}
static __device__ __forceinline__ float bl(unsigned int u) { return __uint_as_float(u << 16); }
static __device__ __forceinline__ float bh(unsigned int u) { return __uint_as_float(u & 0xFFFF0000u); }

// async global->LDS, 16B per lane, no dest VGPRs
static __device__ __forceinline__ void gload16(const void* g, void* l) {
    __builtin_amdgcn_global_load_lds(
        (const __attribute__((address_space(1))) unsigned int*)g,
        (__attribute__((address_space(3))) unsigned int*)l, 16, 0, 0);
}

// ---------------------------------------------------------------------------
// prep megakernel: cast_x (blocks 0..6249) | wpack (6250..6569) |
//                  init gcur + zero stats (6570)
// ---------------------------------------------------------------------------
__global__ __launch_bounds__(256) void prep(const float* __restrict__ x,
                                            const float* __restrict__ Wl1, const float* __restrict__ Wr1,
                                            const float* __restrict__ Wl2, const float* __restrict__ Wr2,
                                            const float* __restrict__ Wl3, const float* __restrict__ Wr3,
                                            unsigned short* __restrict__ xb,
                                            unsigned short* __restrict__ wp,
                                            int* __restrict__ gcur,
                                            float* __restrict__ csz) {
    int b = blockIdx.x, t = threadIdx.x;
    if (b < 6250) {                        // cast x -> bf16 (6250*256 = N*32 exact)
        int idx = b * 256 + t;
        float4 v = ((const float4*)x)[idx];
        uint2 p;
        p.x = (unsigned int)f2b(v.x) | ((unsigned int)f2b(v.y) << 16);
        p.y = (unsigned int)f2b(v.z) | ((unsigned int)f2b(v.w) << 16);
        ((uint2*)xb)[idx] = p;
    } else if (b < 6570) {                 // weight fragment packing (320*256 = 81920)
        int idx = (b - 6250) * 256 + t;
        const float *Wl, *Wr;
        int rel, base;
        if (idx < 32768)       { Wl = Wl1; Wr = Wr1; rel = idx;         base = 0; }
        else if (idx < 65536)  { Wl = Wl2; Wr = Wr2; rel = idx - 32768; base = 32768; }
        else                   { Wl = Wl3; Wr = Wr3; rel = idx - 65536; base = 65536; }
        int o = rel >> 8;
        int k = rel & 255;
        float v = (k < 128) ? Wl[o * 128 + k] : Wr[o * 128 + (k - 128)];
        int nfAll = o >> 4, lr = o & 15;
        int kc = k >> 5, ko = (k >> 3) & 3, kj = k & 7;
        int lane = ko * 16 + lr;
        wp[base + (((nfAll * 8 + kc) * 64 + lane) << 3) + kj] = f2b(v);
    } else {                               // init
        if (t < NB) gcur[t] = t * BCAP;
        csz[t] = 0.f;                      // cs1|cq1
        csz[t + 256] = 0.f;                // cs2|cq2
    }
}

// ---------------------------------------------------------------------------
// CSR build via dense-write bucket sort
// ---------------------------------------------------------------------------
__global__ __launch_bounds__(256) void bucket_scatter(const int* __restrict__ ei,
                                                      int* __restrict__ gcur,
                                                      unsigned int* __restrict__ bdata) {
    __shared__ int hist[NB];
    __shared__ int lcur[NB];
    int t = threadIdx.x;
    if (t < NB) hist[t] = 0;
    __syncthreads();
    int e0 = blockIdx.x * EPB;
    for (int i = t; i < EPB; i += 256) {
        int d = ei[N_EDGES + e0 + i];
        atomicAdd(&hist[d >> 8], 1);
    }
    __syncthreads();
    if (t < NB) lcur[t] = atomicAdd(&gcur[t], hist[t]);
    __syncthreads();
    for (int i = t; i < EPB; i += 256) {
        int d = ei[N_EDGES + e0 + i];
        int s = ei[e0 + i];
        int b = d >> 8;
        int p = atomicAdd(&lcur[b], 1);
        if (p < (b + 1) * BCAP)                       // capacity guard
            bdata[p] = (unsigned int)s | ((unsigned int)(d & 255) << 16);
    }
}

// One block per bucket: self-scan of bucket totals + local count/scan/fill.
__global__ __launch_bounds__(256) void bucket_fill(const unsigned int* __restrict__ bdata,
                                                   const int* __restrict__ gcur,
                                                   int* __restrict__ row,
                                                   int* __restrict__ csrc) {
    __shared__ unsigned int ent[BCAP];
    __shared__ int lcnt[256];
    __shared__ int sm[256];
    __shared__ int cur[256];
    int b = blockIdx.x;
    int t = threadIdx.x;

    int v = 0;
    if (t < NB) {
        v = gcur[t] - t * BCAP;
        if (v > BCAP) v = BCAP;
    }
    sm[t] = v;
    __syncthreads();
    int x = v;
    for (int off = 1; off < 256; off <<= 1) {
        int y = (t >= off) ? sm[t - off] : 0;
        __syncthreads();
        x += y;
        sm[t] = x;
        __syncthreads();
    }
    int cnt = gcur[b] - b * BCAP;
    if (cnt > BCAP) cnt = BCAP;
    int base = sm[b] - cnt;                // exclusive prefix at b
    if (b == 0 && t == 0) row[N_NODES] = N_EDGES;
    __syncthreads();

    for (int i = t; i < cnt; i += 256) ent[i] = bdata[b * BCAP + i];
    lcnt[t] = 0;
    __syncthreads();
    for (int i = t; i < cnt; i += 256) atomicAdd(&lcnt[(ent[i] >> 16) & 255], 1);
    __syncthreads();
    v = lcnt[t];
    sm[t] = v;
    __syncthreads();
    x = v;
    for (int off = 1; off < 256; off <<= 1) {
        int y = (t >= off) ? sm[t - off] : 0;
        __syncthreads();
        x += y;
        sm[t] = x;
        __syncthreads();
    }
    int pre = x - v;
    int node = b * 256 + t;
    if (node < N_NODES) row[node] = base + pre;
    cur[t] = base + pre;
    __syncthreads();
    for (int i = t; i < cnt; i += 256) {
        unsigned int e = ent[i];
        int p = atomicAdd(&cur[(e >> 16) & 255], 1);
        csrc[p] = (int)(e & 0xFFFFu);
    }
}

// ---------------------------------------------------------------------------
// Mean aggregation: half-wave (32 lanes) per node, UNROLL-8 index-prefetch
// (8 independent 256B row loads in flight per half-wave).
// ACT: BN scale/shift computed inline from (cs,cq,g,be) -> LDS.
// ---------------------------------------------------------------------------
template <bool ACT>
__global__ __launch_bounds__(256) void agg_mean_bf16(const unsigned short* __restrict__ xin,
                                                     const int* __restrict__ row,
                                                     const int* __restrict__ csrc,
                                                     const float* __restrict__ csP,
                                                     const float* __restrict__ cqP,
                                                     const float* __restrict__ gP,
                                                     const float* __restrict__ beP,
                                                     unsigned short* __restrict__ mean) {
    __shared__ float4 sclS[32], shfS[32];
    int t = threadIdx.x;
    int half = t >> 5;
    int hl = t & 31;
    float4 sc{}, sh{};
    if (ACT) {
        if (t < 32) {
            float4 c4 = ((const float4*)csP)[t];
            float4 q4 = ((const float4*)cqP)[t];
            float4 g4 = ((const float4*)gP)[t];
            float4 b4 = ((const float4*)beP)[t];
            const float inv_n = 1.0f / N_NODES;
            float4 s, h;
            float mu;
            mu = c4.x * inv_n; s.x = g4.x * rsqrtf(q4.x * inv_n - mu * mu + BN_EPS); h.x = b4.x - mu * s.x;
            mu = c4.y * inv_n; s.y = g4.y * rsqrtf(q4.y * inv_n - mu * mu + BN_EPS); h.y = b4.y - mu * s.y;
            mu = c4.z * inv_n; s.z = g4.z * rsqrtf(q4.z * inv_n - mu * mu + BN_EPS); h.z = b4.z - mu * s.z;
            mu = c4.w * inv_n; s.w = g4.w * rsqrtf(q4.w * inv_n - mu * mu + BN_EPS); h.w = b4.w - mu * s.w;
            sclS[t] = s;
            shfS[t] = h;
        }
        __syncthreads();
        sc = sclS[hl];
        sh = shfS[hl];
    }
    int node = blockIdx.x * 8 + half;
    if (node >= N_NODES) return;
    int r0 = row[node], r1 = row[node + 1];
    const uint2* x2 = (const uint2*)xin;   // row stride 32 uint2
    float a0 = 0.f, a1 = 0.f, a2 = 0.f, a3 = 0.f;
    auto val = [&](float raw, float s, float h) {
        return ACT ? fmaxf(fmaf(raw, s, h), 0.f) : raw;
    };
    auto accum = [&](uint2 v) {
        a0 += val(bl(v.x), sc.x, sh.x);
        a1 += val(bh(v.x), sc.y, sh.y);
        a2 += val(bl(v.y), sc.z, sh.z);
        a3 += val(bh(v.y), sc.w, sh.w);
    };
    int j = r0;
    for (; j + 7 < r1; j += 8) {           // 8 indices, then 8 independent loads
        int s0 = csrc[j],     s1 = csrc[j + 1], s2 = csrc[j + 2], s3 = csrc[j + 3];
        int s4 = csrc[j + 4], s5 = csrc[j + 5], s6 = csrc[j + 6], s7 = csrc[j + 7];
        uint2 v0 = x2[(size_t)s0 * 32 + hl];
        uint2 v1 = x2[(size_t)s1 * 32 + hl];
        uint2 v2 = x2[(size_t)s2 * 32 + hl];
        uint2 v3 = x2[(size_t)s3 * 32 + hl];
        uint2 v4 = x2[(size_t)s4 * 32 + hl];
        uint2 v5 = x2[(size_t)s5 * 32 + hl];
        uint2 v6 = x2[(size_t)s6 * 32 + hl];
        uint2 v7 = x2[(size_t)s7 * 32 + hl];
        accum(v0); accum(v1); accum(v2); accum(v3);
        accum(v4); accum(v5); accum(v6); accum(v7);
    }
    for (; j + 3 < r1; j += 4) {
        int s0 = csrc[j], s1 = csrc[j + 1], s2 = csrc[j + 2], s3 = csrc[j + 3];
        uint2 v0 = x2[(size_t)s0 * 32 + hl];
        uint2 v1 = x2[(size_t)s1 * 32 + hl];
        uint2 v2 = x2[(size_t)s2 * 32 + hl];
        uint2 v3 = x2[(size_t)s3 * 32 + hl];
        accum(v0); accum(v1); accum(v2); accum(v3);
    }
    for (; j < r1; ++j) {
        accum(x2[(size_t)csrc[j] * 32 + hl]);
    }
    int deg = r1 - r0;
    float inv = 1.0f / (float)(deg > 1 ? deg : 1);
    uint2 pk;
    pk.x = (unsigned int)f2b(a0 * inv) | ((unsigned int)f2b(a1 * inv) << 16);
    pk.y = (unsigned int)f2b(a2 * inv) | ((unsigned int)f2b(a3 * inv) << 16);
    ((uint2*)mean)[(size_t)node * 32 + hl] = pk;
}

// ---------------------------------------------------------------------------
// MFMA dual-GEMM, per-wave counted-vmcnt pipeline (T4, R22 config):
//   4 waves/block, each wave owns a PRIVATE 2x8KB LDS slab double-buffer and
//   a fixed 32-col quarter (cq). issue 8 gload_lds(next) -> vmcnt(8) ->
//   compute current. NO barriers in the loop; waves drift.
// ---------------------------------------------------------------------------
template <int O, bool BF16OUT, bool STATS, bool ACTX>
__global__ __launch_bounds__(256, 1) void gemm_mfma(const unsigned short* __restrict__ Am,
                                                    const unsigned short* __restrict__ Ax,
                                                    const unsigned short* __restrict__ wp,
                                                    const float* __restrict__ bias,
                                                    const float* __restrict__ csP,
                                                    const float* __restrict__ cqP,
                                                    const float* __restrict__ gP,
                                                    const float* __restrict__ beP,
                                                    unsigned short* __restrict__ hout,
                                                    float* __restrict__ fout,
                                                    float* __restrict__ csO,
                                                    float* __restrict__ cqO) {
    constexpr int CH = O / 64;               // 2: col-quarters/wave; 1: col-halves
    __shared__ char lds[65536];              // 4 waves x 2 x 8KB private slabs
    __shared__ float sclS[128], shfS[128];
    int t = threadIdx.x;
    int wv = t >> 6, l = t & 63;
    int lr = l & 15, ko = l >> 4;
    char* wlds = lds + wv * 16384;           // this wave's 16KB region

    // wave task mapping: fixed col quarter cq, slab sequence slab0 + k*sstride
    int cq, slab0, sstride, niter;
    if (CH == 2) { cq = wv;      slab0 = blockIdx.x;                       sstride = GGRID;     niter = 8; }
    else         { cq = wv & 1;  slab0 = blockIdx.x + GGRID * (wv >> 1);   sstride = GGRID * 2; niter = 4; }

    // ---- W fragments + bias -> registers (hoisted; keeps vmem FIFO clean) ----
    uint4 wfr[2][8];
#pragma unroll
    for (int nf = 0; nf < 2; ++nf)
#pragma unroll
        for (int kc = 0; kc < 8; ++kc)
            wfr[nf][kc] = *(const uint4*)(wp + (size_t)(((cq * 2 + nf) * 8 + kc) * 512) + l * 8);
    float bs[2];
#pragma unroll
    for (int nf = 0; nf < 2; ++nf) bs[nf] = bias[cq * 32 + nf * 16 + lr];

    // ---- inline BN prep ----
    if (ACTX && t < 128) {
        const float inv_n = 1.0f / N_NODES;
        float mu = csP[t] * inv_n;
        float var = cqP[t] * inv_n - mu * mu;
        float sc = gP[t] * rsqrtf(var + BN_EPS);
        sclS[t] = sc;
        shfS[t] = beP[t] - mu * sc;
    }

    // ---- stage one 16-row slab (mn 4KB | x 4KB) into buf (8 x 1KB DMA) ----
    auto STAGE = [&](int buf, int slab) {
        char* bd = wlds + buf * 8192;
        int rbase = slab * 16;
#pragma unroll
        for (int i = 0; i < 8; ++i) {
            int half = i >> 2;
            int rloc = (i & 3) * 4 + (l >> 4);        // 0..15
            int clog = (l & 15) ^ rloc;               // inverse nibble swizzle
            const unsigned short* src = half ? Ax : Am;
            gload16(src + (size_t)(rbase + rloc) * 128 + clog * 8, bd + i * 1024);
        }
    };

    if (slab0 < NSLAB) STAGE(0, slab0);
    __syncthreads();                         // one-time: BN LDS visible; DMA drained

    float sacc[2] = {0.f, 0.f}, qacc[2] = {0.f, 0.f};

#pragma unroll 1
    for (int k = 0; k < niter; ++k) {
        int scur = slab0 + k * sstride;
        int snxt = scur + sstride;
        if (k + 1 < niter && snxt < NSLAB) STAGE((k + 1) & 1, snxt);
        if (scur >= NSLAB) continue;

        // wait current slab's DMA (<=8 outstanding = next slab's loads only)
        asm volatile("s_waitcnt vmcnt(8)" ::: "memory");

        const char* ab = wlds + (k & 1) * 8192;
        f32x4 acc[2];
        acc[0] = (f32x4){0.f, 0.f, 0.f, 0.f};
        acc[1] = (f32x4){0.f, 0.f, 0.f, 0.f};
#pragma unroll
        for (int kc = 0; kc < 8; ++kc) {
            int clog = (kc & 3) * 4 + ko;
            int cphys = clog ^ lr;                    // nibble swizzle (rows 0..15)
            bf16x8 af = *(const bf16x8*)(ab + (kc >> 2) * 4096 + lr * 256 + cphys * 16);
            if (ACTX && kc >= 4) {           // fused prev-layer BN+ReLU on self
                int f0 = clog * 8;
                float4 s0 = *(const float4*)(sclS + f0);
                float4 s1 = *(const float4*)(sclS + f0 + 4);
                float4 h0 = *(const float4*)(shfS + f0);
                float4 h1 = *(const float4*)(shfS + f0 + 4);
                uint4 u = *(uint4*)&af;
                uint4 r;
                float e0 = fmaxf(fmaf(bl(u.x), s0.x, h0.x), 0.f);
                float e1 = fmaxf(fmaf(bh(u.x), s0.y, h0.y), 0.f);
                float e2 = fmaxf(fmaf(bl(u.y), s0.z, h0.z), 0.f);
                float e3 = fmaxf(fmaf(bh(u.y), s0.w, h0.w), 0.f);
                float e4 = fmaxf(fmaf(bl(u.z), s1.x, h1.x), 0.f);
                float e5 = fmaxf(fmaf(bh(u.z), s1.y, h1.y), 0.f);
                float e6 = fmaxf(fmaf(bl(u.w), s1.z, h1.z), 0.f);
                float e7 = fmaxf(fmaf(bh(u.w), s1.w, h1.w), 0.f);
                r.x = (unsigned int)f2b(e0) | ((unsigned int)f2b(e1) << 16);
                r.y = (unsigned int)f2b(e2) | ((unsigned int)f2b(e3) << 16);
                r.z = (unsigned int)f2b(e4) | ((unsigned int)f2b(e5) << 16);
                r.w = (unsigned int)f2b(e6) | ((unsigned int)f2b(e7) << 16);
                af = *(bf16x8*)&r;
            }
#pragma unroll
            for (int nf = 0; nf < 2; ++nf) {
                bf16x8 wf = *(bf16x8*)&wfr[nf][kc];
                acc[nf] = __builtin_amdgcn_mfma_f32_16x16x32_bf16(af, wf, acc[nf], 0, 0, 0);
            }
        }

        // epilogue: bias + store + stats
        int orow0 = scur * 16 + ko * 4;
#pragma unroll
        for (int nf = 0; nf < 2; ++nf) {
            int col = cq * 32 + nf * 16 + lr;
#pragma unroll
            for (int j = 0; j < 4; ++j) {
                int r = orow0 + j;
                float v = acc[nf][j] + bs[nf];
                if (BF16OUT) hout[(size_t)r * 128 + col] = f2b(v);
                else         fout[(size_t)r * 64 + col] = v;
                if (STATS) { sacc[nf] += v; qacc[nf] += v * v; }
            }
        }
    }

    // ---- stats reduction: one atomic pair per col per wave ----
    if (STATS) {
#pragma unroll
        for (int nf = 0; nf < 2; ++nf) {
            float s = sacc[nf], q = qacc[nf];
            s += __shfl_xor(s, 16);
            s += __shfl_xor(s, 32);
            q += __shfl_xor(q, 16);
            q += __shfl_xor(q, 32);
            if (ko == 0) {
                int col = cq * 32 + nf * 16 + lr;
                atomicAdd(&csO[col], s);
                atomicAdd(&cqO[col], q);
            }
        }
    }
}

// ---------------------------------------------------------------------------
extern "C" void kernel_launch(void* const* d_in, const int* in_sizes, int n_in,
                              void* d_out, int out_size, void* d_ws, size_t ws_size,
                              hipStream_t stream) {
    const float* x   = (const float*)d_in[0];
    const int*   ei  = (const int*)d_in[1];
    const float* Wl1 = (const float*)d_in[2];
    const float* Wr1 = (const float*)d_in[3];
    const float* b1  = (const float*)d_in[4];
    const float* g1  = (const float*)d_in[5];
    const float* be1 = (const float*)d_in[6];
    const float* Wl2 = (const float*)d_in[7];
    const float* Wr2 = (const float*)d_in[8];
    const float* b2  = (const float*)d_in[9];
    const float* g2  = (const float*)d_in[10];
    const float* be2 = (const float*)d_in[11];
    const float* Wl3 = (const float*)d_in[12];
    const float* Wr3 = (const float*)d_in[13];
    const float* b3  = (const float*)d_in[14];
    float* out = (float*)d_out;

    char* p = (char*)d_ws;
    size_t off = 0;
    auto alloc = [&](size_t bytes) {
        char* r = p + off;
        off = (off + bytes + 255) & ~(size_t)255;
        return r;
    };
    int*            gcur  = (int*)alloc((size_t)NB * 4);
    unsigned int*   bdata = (unsigned int*)alloc((size_t)NB * BCAP * 4);
    int*            row   = (int*)alloc((size_t)(N_NODES + 1) * 4);
    int*            csrc  = (int*)alloc((size_t)N_EDGES * 4);
    unsigned short* xb    = (unsigned short*)alloc((size_t)N_NODES * 128 * 2);
    unsigned short* mn    = (unsigned short*)alloc((size_t)N_NODES * 128 * 2);
    unsigned short* h1    = (unsigned short*)alloc((size_t)N_NODES * 128 * 2);
    unsigned short* h2    = (unsigned short*)alloc((size_t)N_NODES * 128 * 2);
    unsigned short* wpb   = (unsigned short*)alloc((size_t)81920 * 2);
    float*          csz   = (float*)alloc(512 * 4);   // cs1|cq1|cs2|cq2
    float*          cs1   = csz;
    float*          cq1   = csz + 128;
    float*          cs2   = csz + 256;
    float*          cq2   = csz + 384;
    (void)ws_size; (void)n_in; (void)in_sizes; (void)out_size;

    unsigned short* wp1 = wpb;
    unsigned short* wp2 = wpb + 32768;
    unsigned short* wp3 = wpb + 65536;

    const int NBLK8 = (N_NODES + 7) / 8;            // 6250

    // prep (cast + wpack + init + zero stats) + CSR build
    prep<<<6571, 256, 0, stream>>>(x, Wl1, Wr1, Wl2, Wr2, Wl3, Wr3, xb, wpb, gcur, csz);
    bucket_scatter<<<SCAT_BLOCKS, 256, 0, stream>>>(ei, gcur, bdata);
    bucket_fill<<<NB, 256, 0, stream>>>(bdata, gcur, row, csrc);

    // Layer 1
    agg_mean_bf16<false><<<NBLK8, 256, 0, stream>>>(
        xb, row, csrc, nullptr, nullptr, nullptr, nullptr, mn);
    gemm_mfma<128, true, true, false><<<GGRID, 256, 0, stream>>>(
        mn, xb, wp1, b1, nullptr, nullptr, nullptr, nullptr, h1, nullptr, cs1, cq1);

    // Layer 2 (h1 raw; BN1+ReLU computed inline in consumers from cs1/cq1)
    agg_mean_bf16<true><<<NBLK8, 256, 0, stream>>>(
        h1, row, csrc, cs1, cq1, g1, be1, mn);
    gemm_mfma<128, true, true, true><<<GGRID, 256, 0, stream>>>(
        mn, h1, wp2, b2, cs1, cq1, g1, be1, h2, nullptr, cs2, cq2);

    // Layer 3 (h2 raw; BN2+ReLU inline from cs2/cq2) -> f32 d_out
    agg_mean_bf16<true><<<NBLK8, 256, 0, stream>>>(
        h2, row, csrc, cs2, cq2, g2, be2, mn);
    gemm_mfma<64, false, false, true><<<GGRID, 256, 0, stream>>>(
        mn, h2, wp3, b3, cs2, cq2, g2, be2, nullptr, out, nullptr, nullptr);
}

// Round 25
// 185.740 us; speedup vs baseline: 1.0090x; 1.0090x over previous
//
#include <hip/hip_runtime.h>

#define N_NODES 50000
#define N_EDGES 800000
#define BN_EPS 1e-5f
#define NB 196          // dst buckets: bucket = dst >> 8
#define BCAP 5120       // bucket capacity (avg 4082, sigma ~64)
#define SCAT_BLOCKS 400 // 2000 edges per block
#define EPB 2000
#define GGRID 391       // gemm blocks
#define NSLAB 3125      // 50000 / 16 exact

typedef __bf16 bf16x8 __attribute__((ext_vector_type(8)));
typedef float f32x4 __attribute__((ext_vector_type(4)));

static __device__ __forceinline__ unsigned short f2b(float f) {
    unsigned int u = __float_as_uint(f);
    return (unsigned short)((u + 0x7FFFu + ((u >> 16) & 1u)) >> 16);   // RNE
}
static __device__ __forceinline__ float bl(unsigned int u) { return __uint_as_float(u << 16); }
static __device__ __forceinline__ float bh(unsigned int u) { return __uint_as_float(u & 0xFFFF0000u); }

// async global->LDS, 16B per lane, no dest VGPRs
static __device__ __forceinline__ void gload16(const void* g, void* l) {
    __builtin_amdgcn_global_load_lds(
        (const __attribute__((address_space(1))) unsigned int*)g,
        (__attribute__((address_space(3))) unsigned int*)l, 16, 0, 0);
}

// ---------------------------------------------------------------------------
// prep megakernel: cast_x (blocks 0..6249) | wpack (6250..6569) |
//                  init gcur + zero stats (6570)
// ---------------------------------------------------------------------------
__global__ __launch_bounds__(256) void prep(const float* __restrict__ x,
                                            const float* __restrict__ Wl1, const float* __restrict__ Wr1,
                                            const float* __restrict__ Wl2, const float* __restrict__ Wr2,
                                            const float* __restrict__ Wl3, const float* __restrict__ Wr3,
                                            unsigned short* __restrict__ xb,
                                            unsigned short* __restrict__ wp,
                                            int* __restrict__ gcur,
                                            float* __restrict__ csz) {
    int b = blockIdx.x, t = threadIdx.x;
    if (b < 6250) {                        // cast x -> bf16 (6250*256 = N*32 exact)
        int idx = b * 256 + t;
        float4 v = ((const float4*)x)[idx];
        uint2 p;
        p.x = (unsigned int)f2b(v.x) | ((unsigned int)f2b(v.y) << 16);
        p.y = (unsigned int)f2b(v.z) | ((unsigned int)f2b(v.w) << 16);
        ((uint2*)xb)[idx] = p;
    } else if (b < 6570) {                 // weight fragment packing (320*256 = 81920)
        int idx = (b - 6250) * 256 + t;
        const float *Wl, *Wr;
        int rel, base;
        if (idx < 32768)       { Wl = Wl1; Wr = Wr1; rel = idx;         base = 0; }
        else if (idx < 65536)  { Wl = Wl2; Wr = Wr2; rel = idx - 32768; base = 32768; }
        else                   { Wl = Wl3; Wr = Wr3; rel = idx - 65536; base = 65536; }
        int o = rel >> 8;
        int k = rel & 255;
        float v = (k < 128) ? Wl[o * 128 + k] : Wr[o * 128 + (k - 128)];
        int nfAll = o >> 4, lr = o & 15;
        int kc = k >> 5, ko = (k >> 3) & 3, kj = k & 7;
        int lane = ko * 16 + lr;
        wp[base + (((nfAll * 8 + kc) * 64 + lane) << 3) + kj] = f2b(v);
    } else {                               // init
        if (t < NB) gcur[t] = t * BCAP;
        csz[t] = 0.f;                      // cs1|cq1
        csz[t + 256] = 0.f;                // cs2|cq2
    }
}

// ---------------------------------------------------------------------------
// CSR build via dense-write bucket sort
// ---------------------------------------------------------------------------
__global__ __launch_bounds__(256) void bucket_scatter(const int* __restrict__ ei,
                                                      int* __restrict__ gcur,
                                                      unsigned int* __restrict__ bdata) {
    __shared__ int hist[NB];
    __shared__ int lcur[NB];
    int t = threadIdx.x;
    if (t < NB) hist[t] = 0;
    __syncthreads();
    int e0 = blockIdx.x * EPB;
    for (int i = t; i < EPB; i += 256) {
        int d = ei[N_EDGES + e0 + i];
        atomicAdd(&hist[d >> 8], 1);
    }
    __syncthreads();
    if (t < NB) lcur[t] = atomicAdd(&gcur[t], hist[t]);
    __syncthreads();
    for (int i = t; i < EPB; i += 256) {
        int d = ei[N_EDGES + e0 + i];
        int s = ei[e0 + i];
        int b = d >> 8;
        int p = atomicAdd(&lcur[b], 1);
        if (p < (b + 1) * BCAP)                       // capacity guard
            bdata[p] = (unsigned int)s | ((unsigned int)(d & 255) << 16);
    }
}

// One block per bucket: self-scan of bucket totals + local count/scan/fill.
__global__ __launch_bounds__(256) void bucket_fill(const unsigned int* __restrict__ bdata,
                                                   const int* __restrict__ gcur,
                                                   int* __restrict__ row,
                                                   int* __restrict__ csrc) {
    __shared__ unsigned int ent[BCAP];
    __shared__ int lcnt[256];
    __shared__ int sm[256];
    __shared__ int cur[256];
    int b = blockIdx.x;
    int t = threadIdx.x;

    int v = 0;
    if (t < NB) {
        v = gcur[t] - t * BCAP;
        if (v > BCAP) v = BCAP;
    }
    sm[t] = v;
    __syncthreads();
    int x = v;
    for (int off = 1; off < 256; off <<= 1) {
        int y = (t >= off) ? sm[t - off] : 0;
        __syncthreads();
        x += y;
        sm[t] = x;
        __syncthreads();
    }
    int cnt = gcur[b] - b * BCAP;
    if (cnt > BCAP) cnt = BCAP;
    int base = sm[b] - cnt;                // exclusive prefix at b
    if (b == 0 && t == 0) row[N_NODES] = N_EDGES;
    __syncthreads();

    for (int i = t; i < cnt; i += 256) ent[i] = bdata[b * BCAP + i];
    lcnt[t] = 0;
    __syncthreads();
    for (int i = t; i < cnt; i += 256) atomicAdd(&lcnt[(ent[i] >> 16) & 255], 1);
    __syncthreads();
    v = lcnt[t];
    sm[t] = v;
    __syncthreads();
    x = v;
    for (int off = 1; off < 256; off <<= 1) {
        int y = (t >= off) ? sm[t - off] : 0;
        __syncthreads();
        x += y;
        sm[t] = x;
        __syncthreads();
    }
    int pre = x - v;
    int node = b * 256 + t;
    if (node < N_NODES) row[node] = base + pre;
    cur[t] = base + pre;
    __syncthreads();
    for (int i = t; i < cnt; i += 256) {
        unsigned int e = ent[i];
        int p = atomicAdd(&cur[(e >> 16) & 255], 1);
        csrc[p] = (int)(e & 0xFFFFu);
    }
}

// ---------------------------------------------------------------------------
// Mean aggregation: half-wave (32 lanes) per node, UNROLL-4 with index
// prefetch (4 independent 256B row loads in flight per half-wave).
// ACT: BN scale/shift computed inline from (cs,cq,g,be) -> LDS.
// ---------------------------------------------------------------------------
template <bool ACT>
__global__ __launch_bounds__(256) void agg_mean_bf16(const unsigned short* __restrict__ xin,
                                                     const int* __restrict__ row,
                                                     const int* __restrict__ csrc,
                                                     const float* __restrict__ csP,
                                                     const float* __restrict__ cqP,
                                                     const float* __restrict__ gP,
                                                     const float* __restrict__ beP,
                                                     unsigned short* __restrict__ mean) {
    __shared__ float4 sclS[32], shfS[32];
    int t = threadIdx.x;
    int half = t >> 5;
    int hl = t & 31;
    float4 sc{}, sh{};
    if (ACT) {
        if (t < 32) {
            float4 c4 = ((const float4*)csP)[t];
            float4 q4 = ((const float4*)cqP)[t];
            float4 g4 = ((const float4*)gP)[t];
            float4 b4 = ((const float4*)beP)[t];
            const float inv_n = 1.0f / N_NODES;
            float4 s, h;
            float mu;
            mu = c4.x * inv_n; s.x = g4.x * rsqrtf(q4.x * inv_n - mu * mu + BN_EPS); h.x = b4.x - mu * s.x;
            mu = c4.y * inv_n; s.y = g4.y * rsqrtf(q4.y * inv_n - mu * mu + BN_EPS); h.y = b4.y - mu * s.y;
            mu = c4.z * inv_n; s.z = g4.z * rsqrtf(q4.z * inv_n - mu * mu + BN_EPS); h.z = b4.z - mu * s.z;
            mu = c4.w * inv_n; s.w = g4.w * rsqrtf(q4.w * inv_n - mu * mu + BN_EPS); h.w = b4.w - mu * s.w;
            sclS[t] = s;
            shfS[t] = h;
        }
        __syncthreads();
        sc = sclS[hl];
        sh = shfS[hl];
    }
    int node = blockIdx.x * 8 + half;
    if (node >= N_NODES) return;
    int r0 = row[node], r1 = row[node + 1];
    const uint2* x2 = (const uint2*)xin;   // row stride 32 uint2
    float a0 = 0.f, a1 = 0.f, a2 = 0.f, a3 = 0.f;
    auto val = [&](float raw, float s, float h) {
        return ACT ? fmaxf(fmaf(raw, s, h), 0.f) : raw;
    };
    int j = r0;
    for (; j + 3 < r1; j += 4) {           // 4 indices, then 4 independent loads
        int s0 = csrc[j];
        int s1 = csrc[j + 1];
        int s2 = csrc[j + 2];
        int s3 = csrc[j + 3];
        uint2 v0 = x2[(size_t)s0 * 32 + hl];
        uint2 v1 = x2[(size_t)s1 * 32 + hl];
        uint2 v2 = x2[(size_t)s2 * 32 + hl];
        uint2 v3 = x2[(size_t)s3 * 32 + hl];
        a0 += val(bl(v0.x), sc.x, sh.x) + val(bl(v1.x), sc.x, sh.x)
            + val(bl(v2.x), sc.x, sh.x) + val(bl(v3.x), sc.x, sh.x);
        a1 += val(bh(v0.x), sc.y, sh.y) + val(bh(v1.x), sc.y, sh.y)
            + val(bh(v2.x), sc.y, sh.y) + val(bh(v3.x), sc.y, sh.y);
        a2 += val(bl(v0.y), sc.z, sh.z) + val(bl(v1.y), sc.z, sh.z)
            + val(bl(v2.y), sc.z, sh.z) + val(bl(v3.y), sc.z, sh.z);
        a3 += val(bh(v0.y), sc.w, sh.w) + val(bh(v1.y), sc.w, sh.w)
            + val(bh(v2.y), sc.w, sh.w) + val(bh(v3.y), sc.w, sh.w);
    }
    for (; j < r1; ++j) {
        uint2 v = x2[(size_t)csrc[j] * 32 + hl];
        a0 += val(bl(v.x), sc.x, sh.x);
        a1 += val(bh(v.x), sc.y, sh.y);
        a2 += val(bl(v.y), sc.z, sh.z);
        a3 += val(bh(v.y), sc.w, sh.w);
    }
    int deg = r1 - r0;
    float inv = 1.0f / (float)(deg > 1 ? deg : 1);
    uint2 pk;
    pk.x = (unsigned int)f2b(a0 * inv) | ((unsigned int)f2b(a1 * inv) << 16);
    pk.y = (unsigned int)f2b(a2 * inv) | ((unsigned int)f2b(a3 * inv) << 16);
    ((uint2*)mean)[(size_t)node * 32 + hl] = pk;
}

// ---------------------------------------------------------------------------
// MFMA dual-GEMM, per-wave counted-vmcnt pipeline (T4, R22 config):
//   4 waves/block, each wave owns a PRIVATE 2x8KB LDS slab double-buffer and
//   a fixed 32-col quarter (cq). issue 8 gload_lds(next) -> vmcnt(8) ->
//   compute current. NO barriers in the loop; waves drift.
// ---------------------------------------------------------------------------
template <int O, bool BF16OUT, bool STATS, bool ACTX>
__global__ __launch_bounds__(256, 1) void gemm_mfma(const unsigned short* __restrict__ Am,
                                                    const unsigned short* __restrict__ Ax,
                                                    const unsigned short* __restrict__ wp,
                                                    const float* __restrict__ bias,
                                                    const float* __restrict__ csP,
                                                    const float* __restrict__ cqP,
                                                    const float* __restrict__ gP,
                                                    const float* __restrict__ beP,
                                                    unsigned short* __restrict__ hout,
                                                    float* __restrict__ fout,
                                                    float* __restrict__ csO,
                                                    float* __restrict__ cqO) {
    constexpr int CH = O / 64;               // 2: col-quarters/wave; 1: col-halves
    __shared__ char lds[65536];              // 4 waves x 2 x 8KB private slabs
    __shared__ float sclS[128], shfS[128];
    int t = threadIdx.x;
    int wv = t >> 6, l = t & 63;
    int lr = l & 15, ko = l >> 4;
    char* wlds = lds + wv * 16384;           // this wave's 16KB region

    // wave task mapping: fixed col quarter cq, slab sequence slab0 + k*sstride
    int cq, slab0, sstride, niter;
    if (CH == 2) { cq = wv;      slab0 = blockIdx.x;                       sstride = GGRID;     niter = 8; }
    else         { cq = wv & 1;  slab0 = blockIdx.x + GGRID * (wv >> 1);   sstride = GGRID * 2; niter = 4; }

    // ---- W fragments + bias -> registers (hoisted; keeps vmem FIFO clean) ----
    uint4 wfr[2][8];
#pragma unroll
    for (int nf = 0; nf < 2; ++nf)
#pragma unroll
        for (int kc = 0; kc < 8; ++kc)
            wfr[nf][kc] = *(const uint4*)(wp + (size_t)(((cq * 2 + nf) * 8 + kc) * 512) + l * 8);
    float bs[2];
#pragma unroll
    for (int nf = 0; nf < 2; ++nf) bs[nf] = bias[cq * 32 + nf * 16 + lr];

    // ---- inline BN prep ----
    if (ACTX && t < 128) {
        const float inv_n = 1.0f / N_NODES;
        float mu = csP[t] * inv_n;
        float var = cqP[t] * inv_n - mu * mu;
        float sc = gP[t] * rsqrtf(var + BN_EPS);
        sclS[t] = sc;
        shfS[t] = beP[t] - mu * sc;
    }

    // ---- stage one 16-row slab (mn 4KB | x 4KB) into buf (8 x 1KB DMA) ----
    auto STAGE = [&](int buf, int slab) {
        char* bd = wlds + buf * 8192;
        int rbase = slab * 16;
#pragma unroll
        for (int i = 0; i < 8; ++i) {
            int half = i >> 2;
            int rloc = (i & 3) * 4 + (l >> 4);        // 0..15
            int clog = (l & 15) ^ rloc;               // inverse nibble swizzle
            const unsigned short* src = half ? Ax : Am;
            gload16(src + (size_t)(rbase + rloc) * 128 + clog * 8, bd + i * 1024);
        }
    };

    if (slab0 < NSLAB) STAGE(0, slab0);
    __syncthreads();                         // one-time: BN LDS visible; DMA drained

    float sacc[2] = {0.f, 0.f}, qacc[2] = {0.f, 0.f};

#pragma unroll 1
    for (int k = 0; k < niter; ++k) {
        int scur = slab0 + k * sstride;
        int snxt = scur + sstride;
        if (k + 1 < niter && snxt < NSLAB) STAGE((k + 1) & 1, snxt);
        if (scur >= NSLAB) continue;

        // wait current slab's DMA (<=8 outstanding = next slab's loads only)
        asm volatile("s_waitcnt vmcnt(8)" ::: "memory");

        const char* ab = wlds + (k & 1) * 8192;
        f32x4 acc[2];
        acc[0] = (f32x4){0.f, 0.f, 0.f, 0.f};
        acc[1] = (f32x4){0.f, 0.f, 0.f, 0.f};
#pragma unroll
        for (int kc = 0; kc < 8; ++kc) {
            int clog = (kc & 3) * 4 + ko;
            int cphys = clog ^ lr;                    // nibble swizzle (rows 0..15)
            bf16x8 af = *(const bf16x8*)(ab + (kc >> 2) * 4096 + lr * 256 + cphys * 16);
            if (ACTX && kc >= 4) {           // fused prev-layer BN+ReLU on self
                int f0 = clog * 8;
                float4 s0 = *(const float4*)(sclS + f0);
                float4 s1 = *(const float4*)(sclS + f0 + 4);
                float4 h0 = *(const float4*)(shfS + f0);
                float4 h1 = *(const float4*)(shfS + f0 + 4);
                uint4 u = *(uint4*)&af;
                uint4 r;
                float e0 = fmaxf(fmaf(bl(u.x), s0.x, h0.x), 0.f);
                float e1 = fmaxf(fmaf(bh(u.x), s0.y, h0.y), 0.f);
                float e2 = fmaxf(fmaf(bl(u.y), s0.z, h0.z), 0.f);
                float e3 = fmaxf(fmaf(bh(u.y), s0.w, h0.w), 0.f);
                float e4 = fmaxf(fmaf(bl(u.z), s1.x, h1.x), 0.f);
                float e5 = fmaxf(fmaf(bh(u.z), s1.y, h1.y), 0.f);
                float e6 = fmaxf(fmaf(bl(u.w), s1.z, h1.z), 0.f);
                float e7 = fmaxf(fmaf(bh(u.w), s1.w, h1.w), 0.f);
                r.x = (unsigned int)f2b(e0) | ((unsigned int)f2b(e1) << 16);
                r.y = (unsigned int)f2b(e2) | ((unsigned int)f2b(e3) << 16);
                r.z = (unsigned int)f2b(e4) | ((unsigned int)f2b(e5) << 16);
                r.w = (unsigned int)f2b(e6) | ((unsigned int)f2b(e7) << 16);
                af = *(bf16x8*)&r;
            }
#pragma unroll
            for (int nf = 0; nf < 2; ++nf) {
                bf16x8 wf = *(bf16x8*)&wfr[nf][kc];
                acc[nf] = __builtin_amdgcn_mfma_f32_16x16x32_bf16(af, wf, acc[nf], 0, 0, 0);
            }
        }

        // epilogue: bias + store + stats
        int orow0 = scur * 16 + ko * 4;
#pragma unroll
        for (int nf = 0; nf < 2; ++nf) {
            int col = cq * 32 + nf * 16 + lr;
#pragma unroll
            for (int j = 0; j < 4; ++j) {
                int r = orow0 + j;
                float v = acc[nf][j] + bs[nf];
                if (BF16OUT) hout[(size_t)r * 128 + col] = f2b(v);
                else         fout[(size_t)r * 64 + col] = v;
                if (STATS) { sacc[nf] += v; qacc[nf] += v * v; }
            }
        }
    }

    // ---- stats reduction: one atomic pair per col per wave ----
    if (STATS) {
#pragma unroll
        for (int nf = 0; nf < 2; ++nf) {
            float s = sacc[nf], q = qacc[nf];
            s += __shfl_xor(s, 16);
            s += __shfl_xor(s, 32);
            q += __shfl_xor(q, 16);
            q += __shfl_xor(q, 32);
            if (ko == 0) {
                int col = cq * 32 + nf * 16 + lr;
                atomicAdd(&csO[col], s);
                atomicAdd(&cqO[col], q);
            }
        }
    }
}

// ---------------------------------------------------------------------------
extern "C" void kernel_launch(void* const* d_in, const int* in_sizes, int n_in,
                              void* d_out, int out_size, void* d_ws, size_t ws_size,
                              hipStream_t stream) {
    const float* x   = (const float*)d_in[0];
    const int*   ei  = (const int*)d_in[1];
    const float* Wl1 = (const float*)d_in[2];
    const float* Wr1 = (const float*)d_in[3];
    const float* b1  = (const float*)d_in[4];
    const float* g1  = (const float*)d_in[5];
    const float* be1 = (const float*)d_in[6];
    const float* Wl2 = (const float*)d_in[7];
    const float* Wr2 = (const float*)d_in[8];
    const float* b2  = (const float*)d_in[9];
    const float* g2  = (const float*)d_in[10];
    const float* be2 = (const float*)d_in[11];
    const float* Wl3 = (const float*)d_in[12];
    const float* Wr3 = (const float*)d_in[13];
    const float* b3  = (const float*)d_in[14];
    float* out = (float*)d_out;

    char* p = (char*)d_ws;
    size_t off = 0;
    auto alloc = [&](size_t bytes) {
        char* r = p + off;
        off = (off + bytes + 255) & ~(size_t)255;
        return r;
    };
    int*            gcur  = (int*)alloc((size_t)NB * 4);
    unsigned int*   bdata = (unsigned int*)alloc((size_t)NB * BCAP * 4);
    int*            row   = (int*)alloc((size_t)(N_NODES + 1) * 4);
    int*            csrc  = (int*)alloc((size_t)N_EDGES * 4);
    unsigned short* xb    = (unsigned short*)alloc((size_t)N_NODES * 128 * 2);
    unsigned short* mn    = (unsigned short*)alloc((size_t)N_NODES * 128 * 2);
    unsigned short* h1    = (unsigned short*)alloc((size_t)N_NODES * 128 * 2);
    unsigned short* h2    = (unsigned short*)alloc((size_t)N_NODES * 128 * 2);
    unsigned short* wpb   = (unsigned short*)alloc((size_t)81920 * 2);
    float*          csz   = (float*)alloc(512 * 4);   // cs1|cq1|cs2|cq2
    float*          cs1   = csz;
    float*          cq1   = csz + 128;
    float*          cs2   = csz + 256;
    float*          cq2   = csz + 384;
    (void)ws_size; (void)n_in; (void)in_sizes; (void)out_size;

    unsigned short* wp1 = wpb;
    unsigned short* wp2 = wpb + 32768;
    unsigned short* wp3 = wpb + 65536;

    const int NBLK8 = (N_NODES + 7) / 8;            // 6250

    // prep (cast + wpack + init + zero stats) + CSR build
    prep<<<6571, 256, 0, stream>>>(x, Wl1, Wr1, Wl2, Wr2, Wl3, Wr3, xb, wpb, gcur, csz);
    bucket_scatter<<<SCAT_BLOCKS, 256, 0, stream>>>(ei, gcur, bdata);
    bucket_fill<<<NB, 256, 0, stream>>>(bdata, gcur, row, csrc);

    // Layer 1
    agg_mean_bf16<false><<<NBLK8, 256, 0, stream>>>(
        xb, row, csrc, nullptr, nullptr, nullptr, nullptr, mn);
    gemm_mfma<128, true, true, false><<<GGRID, 256, 0, stream>>>(
        mn, xb, wp1, b1, nullptr, nullptr, nullptr, nullptr, h1, nullptr, cs1, cq1);

    // Layer 2 (h1 raw; BN1+ReLU computed inline in consumers from cs1/cq1)
    agg_mean_bf16<true><<<NBLK8, 256, 0, stream>>>(
        h1, row, csrc, cs1, cq1, g1, be1, mn);
    gemm_mfma<128, true, true, true><<<GGRID, 256, 0, stream>>>(
        mn, h1, wp2, b2, cs1, cq1, g1, be1, h2, nullptr, cs2, cq2);

    // Layer 3 (h2 raw; BN2+ReLU inline from cs2/cq2) -> f32 d_out
    agg_mean_bf16<true><<<NBLK8, 256, 0, stream>>>(
        h2, row, csrc, cs2, cq2, g2, be2, mn);
    gemm_mfma<64, false, false, true><<<GGRID, 256, 0, stream>>>(
        mn, h2, wp3, b3, cs2, cq2, g2, be2, nullptr, out, nullptr, nullptr);
}